// Round 8
// baseline (1327.451 us; speedup 1.0000x reference)
//
#include <hip/hip_runtime.h>
#include <math.h>

#define HDIM 512
#define NCH 16
#define BETA 25.0f
#define NKH 48             // 48 K-halves of 32: pairs (hi*hi, hi*lo) then lo*hi

typedef unsigned short ushort_t;
typedef __attribute__((ext_vector_type(8))) short short8;
typedef __attribute__((ext_vector_type(4))) float f32x4;

__device__ __forceinline__ ushort_t f2bf(float f) {
    unsigned u = __float_as_uint(f);
    unsigned r = (u + 0x7fff + ((u >> 16) & 1)) >> 16;
    return (ushort_t)r;
}
__device__ __forceinline__ float bf2f(ushort_t b) {
    return __uint_as_float(((unsigned)b) << 16);
}
__device__ __forceinline__ void split_bf(float v, ushort_t& hi, ushort_t& lo) {
    hi = f2bf(v);
    lo = f2bf(v - bf2f(hi));
}

__device__ __forceinline__ void softplus_jet(float v, float& phi, float& s, float& pp) {
    float y = BETA * v;
    float e = expf(-fabsf(y));
    float inv = 1.0f / (1.0f + e);
    s = (y >= 0.0f) ? inv : e * inv;          // sigmoid(25 v) == phi'
    phi = (fmaxf(y, 0.0f) + log1pf(e)) * (1.0f / BETA);
    pp = BETA * s * (1.0f - s);               // phi''
}

__device__ __forceinline__ void gl_lds16(const void* g, void* l) {
    __builtin_amdgcn_global_load_lds(
        (const __attribute__((address_space(1))) unsigned int*)g,
        (__attribute__((address_space(3))) unsigned int*)l, 16, 0, 0);
}

// ---------------- layer 0: build initial jet in A-format (bf16 hi|lo) ----------------
__global__ __launch_bounds__(256) void layer0_jet(
    const float* __restrict__ x, const float* __restrict__ W0,
    const float* __restrict__ b0, ushort_t* __restrict__ A0)
{
    __shared__ ushort_t sm[16 * 1024];   // 32 KB: rows c, cols [hi(512)|lo(512)]
    int p = blockIdx.x, tid = threadIdx.x;
    float4 z = *reinterpret_cast<const float4*>(&x[p * 4]);
#pragma unroll
    for (int half = 0; half < 2; ++half) {
        int n = half * 256 + tid;
        float4 w = *reinterpret_cast<const float4*>(&W0[n * 4]);
        float v = fmaf(w.x, z.x, fmaf(w.y, z.y, fmaf(w.z, z.z, fmaf(w.w, z.w, b0[n]))));
        float phi, s, pp;
        softplus_jet(v, phi, s, pp);
        float wa[4] = {w.x, w.y, w.z, w.w};
        float o[16];
        o[0] = phi;
#pragma unroll
        for (int a = 0; a < 4; ++a) o[1 + a] = s * wa[a];
        int idx = 5;
#pragma unroll
        for (int a = 0; a < 4; ++a)
#pragma unroll
            for (int b = a; b < 4; ++b) { o[idx] = pp * wa[a] * wa[b]; ++idx; }
        o[15] = 0.0f;
#pragma unroll
        for (int c = 0; c < 16; ++c) {
            ushort_t hb, lb;
            split_bf(o[c], hb, lb);
            sm[c * 1024 + n] = hb;
            sm[c * 1024 + 512 + n] = lb;
        }
    }
    __syncthreads();
    uint4* d4 = reinterpret_cast<uint4*>(A0 + (size_t)p * 16 * 1024);
    const uint4* s4 = reinterpret_cast<const uint4*>(sm);
#pragma unroll
    for (int i = 0; i < 8; ++i) d4[tid + 256 * i] = s4[tid + 256 * i];
}

// ---------------- 256x128 GEMM, 4 waves, 2 blocks/CU, ring-3 + fused jet epilogue ----
// A: [M][1024] bf16 (hi|lo), BT: [512 n][1024] bf16 (hi|lo), M = pts*16
// K-order (48 halves of 32): g<32: pair(h=g>>1): A_hi(h) x (g&1 ? B_lo(h) : B_hi(h))
//                            g>=32: A_lo(g-32) x B_hi(g-32)
//   -> duplicate A_hi fetch is an IMMEDIATE L2-hot re-read.
// LDS ring-3 per operand, 16B-chunk source-swizzled (LDS dest linear, rule 21).
// Ledger: stage A(g+2)@qm0(g) [4 ld], B(g+2)@qm1(g) [2 ld]; vmcnt(4)@qm0(g) end
// completes through B(g+1); bar1 gives cross-wave visibility; half g+1 first read
// at qm1(g) top. No vmcnt(0) in-loop (T4). Ring-3 WAR: stage->slot (g-1)%3 whose
// last ds_read was reg-consumed before bar2(g-1) (all waves) -> race-free.
template<int EPI>
__global__ __launch_bounds__(256, 2) void gemm_jet8(
    const ushort_t* __restrict__ Ag, const ushort_t* __restrict__ BT,
    const float* __restrict__ bias, ushort_t* __restrict__ Anext,
    float* __restrict__ Sout)
{
    __shared__ char smem[73728];
    ushort_t* Asl = (ushort_t*)smem;              // 3 slots x [256][32] = 48 KB
    ushort_t* Bsl = (ushort_t*)(smem + 49152);    // 3 slots x [128][32] = 24 KB
    float*    epi = (float*)smem;                 // [64][128] fp32 (reused after K loop)

    const int tid = threadIdx.x;
    const int wave = tid >> 6, lane = tid & 63;
    const int wr = wave >> 1, wc = wave & 1;      // 2M x 2N wave grid

    // bijective XCD swizzle (m204); 4 n-tiles fastest share an A panel on one XCD
    int nwg = gridDim.x, bid = blockIdx.x;
    int q = nwg >> 3, r = nwg & 7;
    int xcd = bid & 7, i8 = bid >> 3;
    int logical = (xcd < r ? xcd * (q + 1) : r * (q + 1) + (xcd - r) * q) + i8;
    const int mt = logical >> 2;
    const int m0 = mt * 256;
    const int n0 = (logical & 3) * 128;

    // staging map: thread covers row rr*64 + wave*16 + (lane>>2), 16B chunk (lane&3);
    // source chunk permuted by row pair ((lane>>3)&3) so stored layout is swizzled.
    const int s_c = (((lane & 3) - ((lane >> 3) & 3)) & 3) * 8;

    f32x4 acc[8][4] = {};

    auto kaof = [](int g) { return (g < 32) ? (g >> 1) * 32 : 512 + (g - 32) * 32; };
    auto kbof = [](int g) { return (g < 32) ? ((g & 1) << 9) + (g >> 1) * 32 : (g - 32) * 32; };

    auto stageA = [&](int g, int slot) {
        if (g >= NKH) g = 0;                      // wrapped tail: slot dead, any data
        int ka = kaof(g);
#pragma unroll
        for (int rr = 0; rr < 4; ++rr) {
            int row = rr * 64 + wave * 16 + (lane >> 2);
            gl_lds16(Ag + (size_t)(m0 + row) * 1024 + ka + s_c,
                     Asl + slot * 8192 + rr * 2048 + wave * 512);
        }
    };
    auto stageB = [&](int g, int slot) {
        if (g >= NKH) g = 0;
        int kb = kbof(g);
#pragma unroll
        for (int rr = 0; rr < 2; ++rr) {
            int row = rr * 64 + wave * 16 + (lane >> 2);
            gl_lds16(BT + (size_t)(n0 + row) * 1024 + kb + s_c,
                     Bsl + slot * 4096 + rr * 2048 + wave * 512);
        }
    };

    // swizzled fragment read offset (elems): row rA, logical k-chunk (lane>>4)
    const int rA = lane & 15;
    const int rd = rA * 32 + ((((lane >> 4) + (rA >> 1)) & 3) * 8);

    // prologue: halves 0,1 -> slots 0,1 (12 loads/thread)
    stageA(0, 0); stageB(0, 0); stageA(1, 1); stageB(1, 1);
    asm volatile("s_waitcnt vmcnt(6)" ::: "memory");   // half 0 complete
    __builtin_amdgcn_s_barrier();
    asm volatile("" ::: "memory");

    short8 afA[4], afB[4], bfr[4];
#pragma unroll
    for (int mi = 0; mi < 4; ++mi)
        afA[mi] = *(const short8*)&Asl[(wr * 128 + mi * 16) * 32 + rd];
#pragma unroll
    for (int ni = 0; ni < 4; ++ni)
        bfr[ni] = *(const short8*)&Bsl[(wc * 64 + ni * 16) * 32 + rd];

    for (int gj = 0; gj < 16; ++gj) {
#pragma unroll
        for (int u = 0; u < 3; ++u) {
            const int g = gj * 3 + u;
            const int s  = u;                 // slot of half g   (3 | 3*gj)
            const int s1 = (u + 1) % 3;       // slot of half g+1
            const int s2 = (u + 2) % 3;       // stage target (g+2)
            // ---- phase qm=0: MFMA(afA,bfr); prefetch afB(g,quad1); stage A(g+2)
#pragma unroll
            for (int mi = 0; mi < 4; ++mi)
                afB[mi] = *(const short8*)&Asl[s * 8192 + (wr * 128 + 64 + mi * 16) * 32 + rd];
            stageA(g + 2, s2);
            asm volatile("s_waitcnt vmcnt(4)" ::: "memory");
            __builtin_amdgcn_s_barrier();
            __builtin_amdgcn_s_setprio(1);
#pragma unroll
            for (int mi = 0; mi < 4; ++mi)
#pragma unroll
                for (int ni = 0; ni < 4; ++ni)
                    acc[mi][ni] = __builtin_amdgcn_mfma_f32_16x16x32_bf16(
                        afA[mi], bfr[ni], acc[mi][ni], 0, 0, 0);
            __builtin_amdgcn_s_setprio(0);
            asm volatile("" ::: "memory");
            __builtin_amdgcn_s_barrier();
            asm volatile("" ::: "memory");
            // ---- phase qm=1: MFMA(afB,bfr); prefetch afA(g+1); stage B(g+2);
            //      post-MFMA reload bfr(g+1)
#pragma unroll
            for (int mi = 0; mi < 4; ++mi)
                afA[mi] = *(const short8*)&Asl[s1 * 8192 + (wr * 128 + mi * 16) * 32 + rd];
            stageB(g + 2, s2);
            __builtin_amdgcn_s_barrier();
            __builtin_amdgcn_s_setprio(1);
#pragma unroll
            for (int mi = 0; mi < 4; ++mi)
#pragma unroll
                for (int ni = 0; ni < 4; ++ni)
                    acc[4 + mi][ni] = __builtin_amdgcn_mfma_f32_16x16x32_bf16(
                        afB[mi], bfr[ni], acc[4 + mi][ni], 0, 0, 0);
            __builtin_amdgcn_s_setprio(0);
#pragma unroll
            for (int ni = 0; ni < 4; ++ni)
                bfr[ni] = *(const short8*)&Bsl[s1 * 4096 + (wc * 64 + ni * 16) * 32 + rd];
            asm volatile("" ::: "memory");
            __builtin_amdgcn_s_barrier();
            asm volatile("" ::: "memory");
        }
    }

    // drain wrapped tail stages before repurposing LDS
    asm volatile("s_waitcnt vmcnt(0) lgkmcnt(0)" ::: "memory");
    __builtin_amdgcn_s_barrier();
    asm volatile("" ::: "memory");

    // ---- epilogue: four 64-row passes (4 points each), transpose + activation ----
    const int pl = lane & 15, ph = lane >> 4;
    const int wxor = (ph & 1) << 4;
#pragma unroll
    for (int h = 0; h < 4; ++h) {
        if (h) { asm volatile("" ::: "memory"); __builtin_amdgcn_s_barrier(); }
        if (wr == (h >> 1)) {
            const int ab = (h & 1) * 4;
#pragma unroll
            for (int lm = 0; lm < 4; ++lm)
#pragma unroll
                for (int ni = 0; ni < 4; ++ni)
#pragma unroll
                    for (int rr = 0; rr < 4; ++rr)
                        epi[(lm * 16 + ph * 4 + rr) * 128 + ((wc * 64 + ni * 16 + pl) ^ wxor)] = acc[ab + lm][ni][rr];
        }
        asm volatile("" ::: "memory");
        __builtin_amdgcn_s_barrier();
        asm volatile("" ::: "memory");
#pragma unroll
        for (int rep = 0; rep < 2; ++rep) {
            int idx = rep * 256 + tid;
            int n = idx & 127, pq = idx >> 7;        // pq in [0,4)
            const float* vp = &epi[pq * 16 * 128];
            float v[15];
#pragma unroll
            for (int c = 0; c < 15; ++c) v[c] = vp[c * 128 + (n ^ (((c >> 2) & 1) << 4))];
            float val = v[0] + bias[n0 + n];
            float phi, s, pp;
            softplus_jet(val, phi, s, pp);
            float o[16];
            o[0] = phi;
            float d[4];
#pragma unroll
            for (int a = 0; a < 4; ++a) { d[a] = v[1 + a]; o[1 + a] = s * d[a]; }
            int ix = 5;
#pragma unroll
            for (int a = 0; a < 4; ++a)
#pragma unroll
                for (int b = a; b < 4; ++b) { o[ix] = pp * d[a] * d[b] + s * v[ix]; ++ix; }
            o[15] = 0.0f;
            size_t prow = (size_t)mt * 16 + h * 4 + pq;   // chunk-local point
            if (EPI == 1) {
                size_t rb = prow * 16 * 1024;
#pragma unroll
                for (int c = 0; c < 16; ++c) {
                    ushort_t hb, lb;
                    split_bf(o[c], hb, lb);
                    Anext[rb + (size_t)c * 1024 + n0 + n] = hb;
                    Anext[rb + (size_t)c * 1024 + 512 + n0 + n] = lb;
                }
            } else {
                float4* op = reinterpret_cast<float4*>(Sout + ((size_t)prow * 512 + n0 + n) * 16);
#pragma unroll
                for (int qq = 0; qq < 4; ++qq)
                    op[qq] = make_float4(o[4*qq], o[4*qq+1], o[4*qq+2], o[4*qq+3]);
            }
        }
    }
}

// ---------------- final layer + trace (validated) ----------------
__global__ __launch_bounds__(256) void trace_kernel(
    const float* __restrict__ Sin, const float* __restrict__ W3,
    const float* __restrict__ b3, float* __restrict__ out, int npts)
{
    int wave = threadIdx.x >> 6;
    int lane = threadIdx.x & 63;
    int p = blockIdx.x * 4 + wave;
    if (p >= npts) return;
    const float* sp = Sin + (size_t)p * (HDIM * NCH);

    float hu[4][10];
#pragma unroll
    for (int m = 0; m < 4; ++m)
#pragma unroll
        for (int qq = 0; qq < 10; ++qq) hu[m][qq] = 0.0f;
    float u4 = 0.0f;

    for (int kk = 0; kk < 8; ++kk) {
        int k = kk * 64 + lane;
        const float* sk = sp + k * NCH;
        float4 s0 = *reinterpret_cast<const float4*>(&sk[0]);
        float4 s1 = *reinterpret_cast<const float4*>(&sk[4]);
        float4 s2 = *reinterpret_cast<const float4*>(&sk[8]);
        float4 s3 = *reinterpret_cast<const float4*>(&sk[12]);
        float hv[10] = {s1.y,s1.z,s1.w, s2.x,s2.y,s2.z,s2.w, s3.x,s3.y,s3.z};
        float w3m[5];
#pragma unroll
        for (int m = 0; m < 5; ++m) w3m[m] = W3[m * HDIM + k];
        u4 = fmaf(w3m[4], s0.x, u4);
#pragma unroll
        for (int m = 0; m < 4; ++m)
#pragma unroll
            for (int qq = 0; qq < 10; ++qq) hu[m][qq] = fmaf(w3m[m], hv[qq], hu[m][qq]);
    }

#pragma unroll
    for (int off = 32; off > 0; off >>= 1) {
#pragma unroll
        for (int m = 0; m < 4; ++m)
#pragma unroll
            for (int qq = 0; qq < 10; ++qq) hu[m][qq] += __shfl_xor(hu[m][qq], off, 64);
        u4 += __shfl_xor(u4, off, 64);
    }

    if (lane == 0) {
        const int Pm[4][4] = {{0,1,2,3},{1,4,5,6},{2,5,7,8},{3,6,8,9}};
        const int Pd[4] = {0, 4, 7, 9};
#pragma unroll
        for (int i = 0; i < 4; ++i) {
            float t1 = hu[i][Pd[0]] + hu[i][Pd[1]] + hu[i][Pd[2]] + hu[i][Pd[3]];
            float t2 = hu[0][Pm[0][i]] + hu[1][Pm[1][i]] + hu[2][Pm[2][i]] + hu[3][Pm[3][i]];
            out[p * 5 + i] = t1 - t2;
        }
        out[p * 5 + 4] = u4 + b3[4];
    }
}

// ---------------- weight prep: W (n,k) -> BT[n][hi(512)|lo(512)] bf16 ----------------
__global__ void prep_B(const float* __restrict__ W1, const float* __restrict__ W2,
                       ushort_t* __restrict__ BT1, ushort_t* __restrict__ BT2)
{
    int tid = blockIdx.x * 256 + threadIdx.x;   // 2*512*512 total
    int l = tid >> 18;
    int i = tid & 262143;
    int n = i >> 9, k = i & 511;
    const float* W = l ? W2 : W1;
    ushort_t* BT = l ? BT2 : BT1;
    float v = W[i];
    ushort_t hb, lb;
    split_bf(v, hb, lb);
    size_t rr = (size_t)n * 1024;
    BT[rr + k] = hb;
    BT[rr + 512 + k] = lb;
}

extern "C" void kernel_launch(void* const* d_in, const int* in_sizes, int n_in,
                              void* d_out, int out_size, void* d_ws, size_t ws_size,
                              hipStream_t stream)
{
    const float* x  = (const float*)d_in[0];
    const float* W0 = (const float*)d_in[1];
    const float* b0 = (const float*)d_in[2];
    const float* W1 = (const float*)d_in[3];
    const float* b1 = (const float*)d_in[4];
    const float* W2 = (const float*)d_in[5];
    const float* b2 = (const float*)d_in[6];
    const float* W3 = (const float*)d_in[7];
    const float* b3 = (const float*)d_in[8];
    float* out = (float*)d_out;

    int B = in_sizes[0] / 4;                    // 16384 points

    ushort_t* BT1 = (ushort_t*)d_ws;            // 512*1024 bf16 each
    ushort_t* BT2 = BT1 + 512 * 1024;
    char* bufbase = (char*)(BT2 + 512 * 1024);

    size_t avail = ws_size - 2ull * 512 * 1024 * sizeof(ushort_t);
    size_t per_pt = 2ull * 32768;               // A0/A1 buffers, 32KB each per point
    int Pc = (int)(avail / per_pt) & ~15;       // multiple of 16 (BM=256 = 16 points)
    if (Pc > 16384) Pc = 16384;
    if (Pc < 16) Pc = 16;

    ushort_t* A0 = (ushort_t*)bufbase;                        // Pc*16*1024
    ushort_t* A1 = (ushort_t*)(bufbase + (size_t)Pc * 32768);
    float* S2 = (float*)A0;                                   // reuse A0 after GEMM1

    prep_B<<<2048, 256, 0, stream>>>(W1, W2, BT1, BT2);

    for (int base = 0; base < B; base += Pc) {
        int np = (B - base < Pc) ? (B - base) : Pc;
        layer0_jet<<<np, 256, 0, stream>>>(x + (size_t)base * 4, W0, b0, A0);
        int nwg = (np / 16) * 4;                // (M/256) * (N/128)
        gemm_jet8<1><<<nwg, 256, 0, stream>>>(A0, BT1, b1, A1, nullptr);
        gemm_jet8<2><<<nwg, 256, 0, stream>>>(A1, BT2, b2, nullptr, S2);
        trace_kernel<<<(np + 3) / 4, 256, 0, stream>>>(S2, W3, b3, out + (size_t)base * 5, np);
    }
}

// Round 9
// 1314.235 us; speedup vs baseline: 1.0101x; 1.0101x over previous
//
#include <hip/hip_runtime.h>
#include <math.h>

#define HDIM 512
#define NCH 16
#define BETA 25.0f
#define NKH 48             // 48 K-halves of 32: pairs (hi*hi, hi*lo) then lo*hi

typedef unsigned short ushort_t;
typedef __attribute__((ext_vector_type(8))) short short8;
typedef __attribute__((ext_vector_type(4))) float f32x4;

__device__ __forceinline__ ushort_t f2bf(float f) {
    unsigned u = __float_as_uint(f);
    unsigned r = (u + 0x7fff + ((u >> 16) & 1)) >> 16;
    return (ushort_t)r;
}
__device__ __forceinline__ float bf2f(ushort_t b) {
    return __uint_as_float(((unsigned)b) << 16);
}
__device__ __forceinline__ void split_bf(float v, ushort_t& hi, ushort_t& lo) {
    hi = f2bf(v);
    lo = f2bf(v - bf2f(hi));
}

__device__ __forceinline__ void softplus_jet(float v, float& phi, float& s, float& pp) {
    float y = BETA * v;
    float e = expf(-fabsf(y));
    float inv = 1.0f / (1.0f + e);
    s = (y >= 0.0f) ? inv : e * inv;          // sigmoid(25 v) == phi'
    phi = (fmaxf(y, 0.0f) + log1pf(e)) * (1.0f / BETA);
    pp = BETA * s * (1.0f - s);               // phi''
}

__device__ __forceinline__ void gl_lds16(const void* g, void* l) {
    __builtin_amdgcn_global_load_lds(
        (const __attribute__((address_space(1))) unsigned int*)g,
        (__attribute__((address_space(3))) unsigned int*)l, 16, 0, 0);
}

// ---------------- layer 0: build initial jet in A-format (bf16 hi|lo) ----------------
__global__ __launch_bounds__(256) void layer0_jet(
    const float* __restrict__ x, const float* __restrict__ W0,
    const float* __restrict__ b0, ushort_t* __restrict__ A0)
{
    __shared__ ushort_t sm[16 * 1024];   // 32 KB: rows c, cols [hi(512)|lo(512)]
    int p = blockIdx.x, tid = threadIdx.x;
    float4 z = *reinterpret_cast<const float4*>(&x[p * 4]);
#pragma unroll
    for (int half = 0; half < 2; ++half) {
        int n = half * 256 + tid;
        float4 w = *reinterpret_cast<const float4*>(&W0[n * 4]);
        float v = fmaf(w.x, z.x, fmaf(w.y, z.y, fmaf(w.z, z.z, fmaf(w.w, z.w, b0[n]))));
        float phi, s, pp;
        softplus_jet(v, phi, s, pp);
        float wa[4] = {w.x, w.y, w.z, w.w};
        float o[16];
        o[0] = phi;
#pragma unroll
        for (int a = 0; a < 4; ++a) o[1 + a] = s * wa[a];
        int idx = 5;
#pragma unroll
        for (int a = 0; a < 4; ++a)
#pragma unroll
            for (int b = a; b < 4; ++b) { o[idx] = pp * wa[a] * wa[b]; ++idx; }
        o[15] = 0.0f;
#pragma unroll
        for (int c = 0; c < 16; ++c) {
            ushort_t hb, lb;
            split_bf(o[c], hb, lb);
            sm[c * 1024 + n] = hb;
            sm[c * 1024 + 512 + n] = lb;
        }
    }
    __syncthreads();
    uint4* d4 = reinterpret_cast<uint4*>(A0 + (size_t)p * 16 * 1024);
    const uint4* s4 = reinterpret_cast<const uint4*>(sm);
#pragma unroll
    for (int i = 0; i < 8; ++i) d4[tid + 256 * i] = s4[tid + 256 * i];
}

// ---------------- 256x256 GEMM, 8 waves, ring-3, 2-phase-distance vmcnt ----------------
// A: [M][1024] bf16 (hi|lo), BT: [512 n][1024] bf16 (hi|lo), M = pts*16
// K-order (48 halves of 32): g<32: h=g>>1: A_hi(h) x (g&1 ? B_lo(h) : B_hi(h))
//                            g>=32: A_lo(g-32) x B_hi(g-32)
// LDS ring-3 per operand of [256][32] subtiles, 16B-chunk source-swizzled
// (LDS dest linear per gl_lds rules; read uses matching swizzle) -> conflict-free.
// Staging: 2 A-loads/thread @qm0, 2 B-loads/thread @qm1 (512 thr cover 16 KB each).
// Ledger (FIFO, per wave): A(g+2)@qm0(g), B(g+2)@qm1(g).
//   qm0(g): vmcnt(4) leaves {B(g+1),A(g+2)} -> waits only A(g+1), issued 2 phases ago.
//   qm1(g): vmcnt(4) leaves {A(g+2),B(g+2)} -> waits only B(g+1), issued 2 phases ago.
// Pre-MFMA barrier after each vmcnt gives cross-wave visibility before any read of
// that half. No vmcnt(0) in-loop (T4). Reg-dbuf: reads at phase t feed phase t+1.
template<int EPI>
__global__ __launch_bounds__(512, 2) void gemm_jet9(
    const ushort_t* __restrict__ Ag, const ushort_t* __restrict__ BT,
    const float* __restrict__ bias, ushort_t* __restrict__ Anext,
    float* __restrict__ Sout)
{
    __shared__ char smem[98304];
    ushort_t* Asl = (ushort_t*)smem;              // 3 slots x [256][32] = 48 KB
    ushort_t* Bsl = (ushort_t*)(smem + 49152);    // 3 slots x [256][32] = 48 KB
    float*    epi = (float*)smem;                 // [64][256] fp32 (reused after K loop)

    const int tid = threadIdx.x;
    const int wave = tid >> 6, lane = tid & 63;
    const int wr = wave >> 2, wc = wave & 3;      // 2M x 4N wave grid

    // bijective XCD swizzle (m204); 2 n-tiles adjacent share an A panel on one XCD
    int nwg = gridDim.x, bid = blockIdx.x;
    int q = nwg >> 3, r = nwg & 7;
    int xcd = bid & 7, i8 = bid >> 3;
    int logical = (xcd < r ? xcd * (q + 1) : r * (q + 1) + (xcd - r) * q) + i8;
    const int mt = logical >> 1;
    const int m0 = mt * 256;
    const int n0 = (logical & 1) * 256;

    // staging: round rr covers rows rr*128 + wave*16 + (lane>>2); physical 16B chunk
    // (lane&3); source chunk permuted by ((lane>>3)&3) so stored layout is swizzled.
    const int s_c = (((lane & 3) - ((lane >> 3) & 3)) & 3) * 8;

    f32x4 acc[8][4] = {};

    auto kaof = [](int g) { return (g < 32) ? (g >> 1) * 32 : 512 + (g - 32) * 32; };
    auto kbof = [](int g) { return (g < 32) ? ((g & 1) << 9) + (g >> 1) * 32 : (g - 32) * 32; };

    auto stageA = [&](int g, int slot) {
        if (g >= NKH) g = 0;                      // wrapped tail: slot dead, any data
        int ka = kaof(g);
#pragma unroll
        for (int rr = 0; rr < 2; ++rr) {
            int row = rr * 128 + wave * 16 + (lane >> 2);
            gl_lds16(Ag + (size_t)(m0 + row) * 1024 + ka + s_c,
                     Asl + slot * 8192 + rr * 4096 + wave * 512);
        }
    };
    auto stageB = [&](int g, int slot) {
        if (g >= NKH) g = 0;
        int kb = kbof(g);
#pragma unroll
        for (int rr = 0; rr < 2; ++rr) {
            int row = rr * 128 + wave * 16 + (lane >> 2);
            gl_lds16(BT + (size_t)(n0 + row) * 1024 + kb + s_c,
                     Bsl + slot * 8192 + rr * 4096 + wave * 512);
        }
    };

    // swizzled fragment read offset (elems): row rA, logical k-chunk (lane>>4)
    const int rA = lane & 15;
    const int rd = rA * 32 + ((((lane >> 4) + (rA >> 1)) & 3) * 8);

    // prologue: halves 0,1 -> slots 0,1 (8 loads/thread)
    stageA(0, 0); stageB(0, 0); stageA(1, 1); stageB(1, 1);
    asm volatile("s_waitcnt vmcnt(4)" ::: "memory");   // half 0 complete
    __builtin_amdgcn_s_barrier();
    asm volatile("" ::: "memory");

    short8 afA[4], afB[4], bfr[4];
#pragma unroll
    for (int mi = 0; mi < 4; ++mi)
        afA[mi] = *(const short8*)&Asl[(wr * 128 + mi * 16) * 32 + rd];
#pragma unroll
    for (int ni = 0; ni < 4; ++ni)
        bfr[ni] = *(const short8*)&Bsl[(wc * 64 + ni * 16) * 32 + rd];

    for (int gj = 0; gj < 16; ++gj) {
#pragma unroll
        for (int u = 0; u < 3; ++u) {
            const int g = gj * 3 + u;
            const int s  = u;                 // slot of half g
            const int s1 = (u + 1) % 3;       // slot of half g+1
            const int s2 = (u + 2) % 3;       // stage target (g+2)
            // ---- phase qm=0: MFMA(afA,bfr); prefetch afB(g,quad1); stage A(g+2);
            //      vmcnt(4) waits only A(g+1) (2-phase distance)
#pragma unroll
            for (int mi = 0; mi < 4; ++mi)
                afB[mi] = *(const short8*)&Asl[s * 8192 + (wr * 128 + 64 + mi * 16) * 32 + rd];
            stageA(g + 2, s2);
            asm volatile("s_waitcnt vmcnt(4)" ::: "memory");
            __builtin_amdgcn_s_barrier();
            __builtin_amdgcn_s_setprio(1);
#pragma unroll
            for (int mi = 0; mi < 4; ++mi)
#pragma unroll
                for (int ni = 0; ni < 4; ++ni)
                    acc[mi][ni] = __builtin_amdgcn_mfma_f32_16x16x32_bf16(
                        afA[mi], bfr[ni], acc[mi][ni], 0, 0, 0);
            __builtin_amdgcn_s_setprio(0);
            asm volatile("" ::: "memory");
            __builtin_amdgcn_s_barrier();
            asm volatile("" ::: "memory");
            // ---- phase qm=1: MFMA(afB,bfr); prefetch afA(g+1); stage B(g+2);
            //      vmcnt(4) waits only B(g+1); post-MFMA reload bfr(g+1)
#pragma unroll
            for (int mi = 0; mi < 4; ++mi)
                afA[mi] = *(const short8*)&Asl[s1 * 8192 + (wr * 128 + mi * 16) * 32 + rd];
            stageB(g + 2, s2);
            asm volatile("s_waitcnt vmcnt(4)" ::: "memory");
            __builtin_amdgcn_s_barrier();
            __builtin_amdgcn_s_setprio(1);
#pragma unroll
            for (int mi = 0; mi < 4; ++mi)
#pragma unroll
                for (int ni = 0; ni < 4; ++ni)
                    acc[4 + mi][ni] = __builtin_amdgcn_mfma_f32_16x16x32_bf16(
                        afB[mi], bfr[ni], acc[4 + mi][ni], 0, 0, 0);
            __builtin_amdgcn_s_setprio(0);
#pragma unroll
            for (int ni = 0; ni < 4; ++ni)
                bfr[ni] = *(const short8*)&Bsl[s1 * 8192 + (wc * 64 + ni * 16) * 32 + rd];
            asm volatile("" ::: "memory");
            __builtin_amdgcn_s_barrier();
            asm volatile("" ::: "memory");
        }
    }

    // drain wrapped tail stages before repurposing LDS
    asm volatile("s_waitcnt vmcnt(0) lgkmcnt(0)" ::: "memory");
    __builtin_amdgcn_s_barrier();
    asm volatile("" ::: "memory");

    // ---- epilogue: four 64-row passes (4 points each), transpose + activation ----
    const int pl = lane & 15, ph = lane >> 4;
    const int wxor = (ph & 1) << 4;
#pragma unroll
    for (int h = 0; h < 4; ++h) {
        if (h) { asm volatile("" ::: "memory"); __builtin_amdgcn_s_barrier(); }
        if (wr == (h >> 1)) {
            const int ab = (h & 1) * 4;
#pragma unroll
            for (int lm = 0; lm < 4; ++lm)
#pragma unroll
                for (int ni = 0; ni < 4; ++ni)
#pragma unroll
                    for (int rr = 0; rr < 4; ++rr)
                        epi[(lm * 16 + ph * 4 + rr) * 256 + ((wc * 64 + ni * 16 + pl) ^ wxor)] = acc[ab + lm][ni][rr];
        }
        asm volatile("" ::: "memory");
        __builtin_amdgcn_s_barrier();
        asm volatile("" ::: "memory");
#pragma unroll
        for (int rep = 0; rep < 2; ++rep) {
            int idx = rep * 512 + tid;
            int n = idx & 255, pq = idx >> 8;        // pq in [0,4)
            const float* vp = &epi[pq * 16 * 256];
            float v[15];
#pragma unroll
            for (int c = 0; c < 15; ++c) v[c] = vp[c * 256 + (n ^ (((c >> 2) & 1) << 4))];
            float val = v[0] + bias[n0 + n];
            float phi, s, pp;
            softplus_jet(val, phi, s, pp);
            float o[16];
            o[0] = phi;
            float d[4];
#pragma unroll
            for (int a = 0; a < 4; ++a) { d[a] = v[1 + a]; o[1 + a] = s * d[a]; }
            int ix = 5;
#pragma unroll
            for (int a = 0; a < 4; ++a)
#pragma unroll
                for (int b = a; b < 4; ++b) { o[ix] = pp * d[a] * d[b] + s * v[ix]; ++ix; }
            o[15] = 0.0f;
            size_t prow = (size_t)mt * 16 + h * 4 + pq;   // chunk-local point
            if (EPI == 1) {
                size_t rb = prow * 16 * 1024;
#pragma unroll
                for (int c = 0; c < 16; ++c) {
                    ushort_t hb, lb;
                    split_bf(o[c], hb, lb);
                    Anext[rb + (size_t)c * 1024 + n0 + n] = hb;
                    Anext[rb + (size_t)c * 1024 + 512 + n0 + n] = lb;
                }
            } else {
                float4* op = reinterpret_cast<float4*>(Sout + ((size_t)prow * 512 + n0 + n) * 16);
#pragma unroll
                for (int qq = 0; qq < 4; ++qq)
                    op[qq] = make_float4(o[4*qq], o[4*qq+1], o[4*qq+2], o[4*qq+3]);
            }
        }
    }
}

// ---------------- final layer + trace (validated) ----------------
__global__ __launch_bounds__(256) void trace_kernel(
    const float* __restrict__ Sin, const float* __restrict__ W3,
    const float* __restrict__ b3, float* __restrict__ out, int npts)
{
    int wave = threadIdx.x >> 6;
    int lane = threadIdx.x & 63;
    int p = blockIdx.x * 4 + wave;
    if (p >= npts) return;
    const float* sp = Sin + (size_t)p * (HDIM * NCH);

    float hu[4][10];
#pragma unroll
    for (int m = 0; m < 4; ++m)
#pragma unroll
        for (int qq = 0; qq < 10; ++qq) hu[m][qq] = 0.0f;
    float u4 = 0.0f;

    for (int kk = 0; kk < 8; ++kk) {
        int k = kk * 64 + lane;
        const float* sk = sp + k * NCH;
        float4 s0 = *reinterpret_cast<const float4*>(&sk[0]);
        float4 s1 = *reinterpret_cast<const float4*>(&sk[4]);
        float4 s2 = *reinterpret_cast<const float4*>(&sk[8]);
        float4 s3 = *reinterpret_cast<const float4*>(&sk[12]);
        float hv[10] = {s1.y,s1.z,s1.w, s2.x,s2.y,s2.z,s2.w, s3.x,s3.y,s3.z};
        float w3m[5];
#pragma unroll
        for (int m = 0; m < 5; ++m) w3m[m] = W3[m * HDIM + k];
        u4 = fmaf(w3m[4], s0.x, u4);
#pragma unroll
        for (int m = 0; m < 4; ++m)
#pragma unroll
            for (int qq = 0; qq < 10; ++qq) hu[m][qq] = fmaf(w3m[m], hv[qq], hu[m][qq]);
    }

#pragma unroll
    for (int off = 32; off > 0; off >>= 1) {
#pragma unroll
        for (int m = 0; m < 4; ++m)
#pragma unroll
            for (int qq = 0; qq < 10; ++qq) hu[m][qq] += __shfl_xor(hu[m][qq], off, 64);
        u4 += __shfl_xor(u4, off, 64);
    }

    if (lane == 0) {
        const int Pm[4][4] = {{0,1,2,3},{1,4,5,6},{2,5,7,8},{3,6,8,9}};
        const int Pd[4] = {0, 4, 7, 9};
#pragma unroll
        for (int i = 0; i < 4; ++i) {
            float t1 = hu[i][Pd[0]] + hu[i][Pd[1]] + hu[i][Pd[2]] + hu[i][Pd[3]];
            float t2 = hu[0][Pm[0][i]] + hu[1][Pm[1][i]] + hu[2][Pm[2][i]] + hu[3][Pm[3][i]];
            out[p * 5 + i] = t1 - t2;
        }
        out[p * 5 + 4] = u4 + b3[4];
    }
}

// ---------------- weight prep: W (n,k) -> BT[n][hi(512)|lo(512)] bf16 ----------------
__global__ void prep_B(const float* __restrict__ W1, const float* __restrict__ W2,
                       ushort_t* __restrict__ BT1, ushort_t* __restrict__ BT2)
{
    int tid = blockIdx.x * 256 + threadIdx.x;   // 2*512*512 total
    int l = tid >> 18;
    int i = tid & 262143;
    int n = i >> 9, k = i & 511;
    const float* W = l ? W2 : W1;
    ushort_t* BT = l ? BT2 : BT1;
    float v = W[i];
    ushort_t hb, lb;
    split_bf(v, hb, lb);
    size_t rr = (size_t)n * 1024;
    BT[rr + k] = hb;
    BT[rr + 512 + k] = lb;
}

extern "C" void kernel_launch(void* const* d_in, const int* in_sizes, int n_in,
                              void* d_out, int out_size, void* d_ws, size_t ws_size,
                              hipStream_t stream)
{
    const float* x  = (const float*)d_in[0];
    const float* W0 = (const float*)d_in[1];
    const float* b0 = (const float*)d_in[2];
    const float* W1 = (const float*)d_in[3];
    const float* b1 = (const float*)d_in[4];
    const float* W2 = (const float*)d_in[5];
    const float* b2 = (const float*)d_in[6];
    const float* W3 = (const float*)d_in[7];
    const float* b3 = (const float*)d_in[8];
    float* out = (float*)d_out;

    int B = in_sizes[0] / 4;                    // 16384 points

    ushort_t* BT1 = (ushort_t*)d_ws;            // 512*1024 bf16 each
    ushort_t* BT2 = BT1 + 512 * 1024;
    char* bufbase = (char*)(BT2 + 512 * 1024);

    size_t avail = ws_size - 2ull * 512 * 1024 * sizeof(ushort_t);
    size_t per_pt = 2ull * 32768;               // A0/A1 buffers, 32KB each per point
    int Pc = (int)(avail / per_pt) & ~15;       // multiple of 16 (BM=256 = 16 points)
    if (Pc > 16384) Pc = 16384;
    if (Pc < 16) Pc = 16;

    ushort_t* A0 = (ushort_t*)bufbase;                        // Pc*16*1024
    ushort_t* A1 = (ushort_t*)(bufbase + (size_t)Pc * 32768);
    float* S2 = (float*)A0;                                   // reuse A0 after GEMM1

    prep_B<<<2048, 256, 0, stream>>>(W1, W2, BT1, BT2);

    for (int base = 0; base < B; base += Pc) {
        int np = (B - base < Pc) ? (B - base) : Pc;
        layer0_jet<<<np, 256, 0, stream>>>(x + (size_t)base * 4, W0, b0, A0);
        int nwg = (np / 16) * 2;                // (M/256) * (N/256)
        gemm_jet9<1><<<nwg, 512, 0, stream>>>(A0, BT1, b1, A1, nullptr);
        gemm_jet9<2><<<nwg, 512, 0, stream>>>(A1, BT2, b2, nullptr, S2);
        trace_kernel<<<(np + 3) / 4, 256, 0, stream>>>(S2, W3, b3, out + (size_t)base * 5, np);
    }
}

// Round 10
// 1313.307 us; speedup vs baseline: 1.0108x; 1.0007x over previous
//
#include <hip/hip_runtime.h>
#include <math.h>

#define HDIM 512
#define NCH 16
#define BETA 25.0f
#define NKH 48             // 48 K-halves of 32: pairs (hi*hi, hi*lo) then lo*hi

typedef unsigned short ushort_t;
typedef __attribute__((ext_vector_type(8))) short short8;
typedef __attribute__((ext_vector_type(4))) float f32x4;

__device__ __forceinline__ ushort_t f2bf(float f) {
    unsigned u = __float_as_uint(f);
    unsigned r = (u + 0x7fff + ((u >> 16) & 1)) >> 16;
    return (ushort_t)r;
}
__device__ __forceinline__ float bf2f(ushort_t b) {
    return __uint_as_float(((unsigned)b) << 16);
}
__device__ __forceinline__ void split_bf(float v, ushort_t& hi, ushort_t& lo) {
    hi = f2bf(v);
    lo = f2bf(v - bf2f(hi));
}

__device__ __forceinline__ void softplus_jet(float v, float& phi, float& s, float& pp) {
    float y = BETA * v;
    float e = expf(-fabsf(y));
    float inv = 1.0f / (1.0f + e);
    s = (y >= 0.0f) ? inv : e * inv;          // sigmoid(25 v) == phi'
    phi = (fmaxf(y, 0.0f) + log1pf(e)) * (1.0f / BETA);
    pp = BETA * s * (1.0f - s);               // phi''
}

__device__ __forceinline__ void gl_lds16(const void* g, void* l) {
    __builtin_amdgcn_global_load_lds(
        (const __attribute__((address_space(1))) unsigned int*)g,
        (__attribute__((address_space(3))) unsigned int*)l, 16, 0, 0);
}

// ---------------- layer 0: build initial jet in A-format (bf16 hi|lo) ----------------
__global__ __launch_bounds__(256) void layer0_jet(
    const float* __restrict__ x, const float* __restrict__ W0,
    const float* __restrict__ b0, ushort_t* __restrict__ A0)
{
    __shared__ ushort_t sm[16 * 1024];   // 32 KB: rows c, cols [hi(512)|lo(512)]
    int p = blockIdx.x, tid = threadIdx.x;
    float4 z = *reinterpret_cast<const float4*>(&x[p * 4]);
#pragma unroll
    for (int half = 0; half < 2; ++half) {
        int n = half * 256 + tid;
        float4 w = *reinterpret_cast<const float4*>(&W0[n * 4]);
        float v = fmaf(w.x, z.x, fmaf(w.y, z.y, fmaf(w.z, z.z, fmaf(w.w, z.w, b0[n]))));
        float phi, s, pp;
        softplus_jet(v, phi, s, pp);
        float wa[4] = {w.x, w.y, w.z, w.w};
        float o[16];
        o[0] = phi;
#pragma unroll
        for (int a = 0; a < 4; ++a) o[1 + a] = s * wa[a];
        int idx = 5;
#pragma unroll
        for (int a = 0; a < 4; ++a)
#pragma unroll
            for (int b = a; b < 4; ++b) { o[idx] = pp * wa[a] * wa[b]; ++idx; }
        o[15] = 0.0f;
#pragma unroll
        for (int c = 0; c < 16; ++c) {
            ushort_t hb, lb;
            split_bf(o[c], hb, lb);
            sm[c * 1024 + n] = hb;
            sm[c * 1024 + 512 + n] = lb;
        }
    }
    __syncthreads();
    uint4* d4 = reinterpret_cast<uint4*>(A0 + (size_t)p * 16 * 1024);
    const uint4* s4 = reinterpret_cast<const uint4*>(sm);
#pragma unroll
    for (int i = 0; i < 8; ++i) d4[tid + 256 * i] = s4[tid + 256 * i];
}

// ---------------- 256x256 GEMM, 8 waves, ring-4, ONE barrier / 32-MFMA phase --------
// A: [M][1024] bf16 (hi|lo), BT: [512 n][1024] bf16 (hi|lo), M = pts*16
// K-order (48 halves of 32): g<32: h=g>>1: A_hi(h) x (g&1 ? B_lo(h) : B_hi(h))
//                            g>=32: A_lo(g-32) x B_hi(g-32)
// LDS ring-4 per operand of [256][32] subtiles (128 KB), 16B-chunk source-swizzled
// (LDS dest linear per gl_lds rules; read uses matching swizzle) -> conflict-free.
// Phase p (one per K-half): {stage A,B(p+2)->slot (p+2)&3 [4 gl_lds]; vmcnt(4)
// [completes slot p+1, issued 1 phase ago]; barrier; ds_read 12xb128 (slot p);
// 32 MFMA}.  ONE barrier/phase is race-free:
//  - visibility: V vmcnt'd slot p's loads at phase p-1 (outstanding 8 -> 4, FIFO
//    completes slot p) BEFORE barrier(p-1); barriers p-1,p precede W's reads.
//  - WAR: stage at phase p overwrites slot p-2, whose reads (phase p-2) completed
//    before each wave's phase-p-2 MFMAs issued, hence before it reached
//    barrier(p-1); W's stage issues only after passing barrier(p-1).
// In-phase ds_reads hide under the PREVIOUS phase's MFMA pipe drain (no post-MFMA
// barrier). No vmcnt(0) in-loop (T4). setprio around MFMA cluster (T5).
template<int EPI>
__global__ __launch_bounds__(512, 2) void gemm_jet10(
    const ushort_t* __restrict__ Ag, const ushort_t* __restrict__ BT,
    const float* __restrict__ bias, ushort_t* __restrict__ Anext,
    float* __restrict__ Sout)
{
    __shared__ char smem[131072];
    ushort_t* Asl = (ushort_t*)smem;              // 4 slots x [256][32] = 64 KB
    ushort_t* Bsl = (ushort_t*)(smem + 65536);    // 4 slots x [256][32] = 64 KB
    float*    epi = (float*)smem;                 // [64][256] fp32 (reused after K loop)

    const int tid = threadIdx.x;
    const int wave = tid >> 6, lane = tid & 63;
    const int wr = wave >> 2, wc = wave & 3;      // 2M x 4N wave grid

    // bijective XCD swizzle (m204); adjacent n-tiles share an A panel on one XCD
    int nwg = gridDim.x, bid = blockIdx.x;
    int q = nwg >> 3, r = nwg & 7;
    int xcd = bid & 7, i8 = bid >> 3;
    int logical = (xcd < r ? xcd * (q + 1) : r * (q + 1) + (xcd - r) * q) + i8;
    const int mt = logical >> 1;
    const int m0 = mt * 256;
    const int n0 = (logical & 1) * 256;

    // staging: round rr covers rows rr*128 + wave*16 + (lane>>2); physical 16B chunk
    // (lane&3); source chunk permuted by ((lane>>3)&3) so stored layout is swizzled.
    const int s_c = (((lane & 3) - ((lane >> 3) & 3)) & 3) * 8;

    f32x4 acc[8][4] = {};

    auto kaof = [](int g) { return (g < 32) ? (g >> 1) * 32 : 512 + (g - 32) * 32; };
    auto kbof = [](int g) { return (g < 32) ? ((g & 1) << 9) + (g >> 1) * 32 : (g - 32) * 32; };

    auto stageA = [&](int g, int slot) {
        if (g >= NKH) g = 0;                      // wrapped tail: slot dead, any data
        int ka = kaof(g);
#pragma unroll
        for (int rr = 0; rr < 2; ++rr) {
            int row = rr * 128 + wave * 16 + (lane >> 2);
            gl_lds16(Ag + (size_t)(m0 + row) * 1024 + ka + s_c,
                     Asl + slot * 8192 + rr * 4096 + wave * 512);
        }
    };
    auto stageB = [&](int g, int slot) {
        if (g >= NKH) g = 0;
        int kb = kbof(g);
#pragma unroll
        for (int rr = 0; rr < 2; ++rr) {
            int row = rr * 128 + wave * 16 + (lane >> 2);
            gl_lds16(BT + (size_t)(n0 + row) * 1024 + kb + s_c,
                     Bsl + slot * 8192 + rr * 4096 + wave * 512);
        }
    };

    // swizzled fragment read offset (elems): row rA, logical k-chunk (lane>>4)
    const int rA = lane & 15;
    const int rd = rA * 32 + ((((lane >> 4) + (rA >> 1)) & 3) * 8);

    // prologue: halves 0,1 -> slots 0,1 (8 loads/thread outstanding; no barrier --
    // phase 0's vmcnt(4) completes halves 0,1 and its barrier publishes them)
    stageA(0, 0); stageB(0, 0); stageA(1, 1); stageB(1, 1);

    for (int gj = 0; gj < 12; ++gj) {
#pragma unroll
        for (int u = 0; u < 4; ++u) {
            const int g = gj * 4 + u;
            const int s  = u;                 // slot of half g (g & 3)
            const int s2 = (u + 2) & 3;       // stage target (g+2)
            stageA(g + 2, s2);
            stageB(g + 2, s2);
            asm volatile("s_waitcnt vmcnt(4)" ::: "memory");
            __builtin_amdgcn_s_barrier();
            asm volatile("" ::: "memory");
            short8 bf[4], a0[4], a1[4];
#pragma unroll
            for (int ni = 0; ni < 4; ++ni)
                bf[ni] = *(const short8*)&Bsl[s * 8192 + (wc * 64 + ni * 16) * 32 + rd];
#pragma unroll
            for (int mi = 0; mi < 4; ++mi)
                a0[mi] = *(const short8*)&Asl[s * 8192 + (wr * 128 + mi * 16) * 32 + rd];
#pragma unroll
            for (int mi = 0; mi < 4; ++mi)
                a1[mi] = *(const short8*)&Asl[s * 8192 + (wr * 128 + 64 + mi * 16) * 32 + rd];
            __builtin_amdgcn_s_setprio(1);
#pragma unroll
            for (int mi = 0; mi < 4; ++mi)
#pragma unroll
                for (int ni = 0; ni < 4; ++ni)
                    acc[mi][ni] = __builtin_amdgcn_mfma_f32_16x16x32_bf16(
                        a0[mi], bf[ni], acc[mi][ni], 0, 0, 0);
#pragma unroll
            for (int mi = 0; mi < 4; ++mi)
#pragma unroll
                for (int ni = 0; ni < 4; ++ni)
                    acc[4 + mi][ni] = __builtin_amdgcn_mfma_f32_16x16x32_bf16(
                        a1[mi], bf[ni], acc[4 + mi][ni], 0, 0, 0);
            __builtin_amdgcn_s_setprio(0);
            asm volatile("" ::: "memory");
        }
    }

    // drain wrapped tail stages before repurposing LDS
    asm volatile("s_waitcnt vmcnt(0) lgkmcnt(0)" ::: "memory");
    __builtin_amdgcn_s_barrier();
    asm volatile("" ::: "memory");

    // ---- epilogue: four 64-row passes (4 points each), transpose + activation ----
    const int pl = lane & 15, ph = lane >> 4;
    const int wxor = (ph & 1) << 4;
#pragma unroll
    for (int h = 0; h < 4; ++h) {
        if (h) { asm volatile("" ::: "memory"); __builtin_amdgcn_s_barrier(); }
        if (wr == (h >> 1)) {
            const int ab = (h & 1) * 4;
#pragma unroll
            for (int lm = 0; lm < 4; ++lm)
#pragma unroll
                for (int ni = 0; ni < 4; ++ni)
#pragma unroll
                    for (int rr = 0; rr < 4; ++rr)
                        epi[(lm * 16 + ph * 4 + rr) * 256 + ((wc * 64 + ni * 16 + pl) ^ wxor)] = acc[ab + lm][ni][rr];
        }
        asm volatile("" ::: "memory");
        __builtin_amdgcn_s_barrier();
        asm volatile("" ::: "memory");
#pragma unroll
        for (int rep = 0; rep < 2; ++rep) {
            int idx = rep * 512 + tid;
            int n = idx & 255, pq = idx >> 8;        // pq in [0,4)
            const float* vp = &epi[pq * 16 * 256];
            float v[15];
#pragma unroll
            for (int c = 0; c < 15; ++c) v[c] = vp[c * 256 + (n ^ (((c >> 2) & 1) << 4))];
            float val = v[0] + bias[n0 + n];
            float phi, s, pp;
            softplus_jet(val, phi, s, pp);
            float o[16];
            o[0] = phi;
            float d[4];
#pragma unroll
            for (int a = 0; a < 4; ++a) { d[a] = v[1 + a]; o[1 + a] = s * d[a]; }
            int ix = 5;
#pragma unroll
            for (int a = 0; a < 4; ++a)
#pragma unroll
                for (int b = a; b < 4; ++b) { o[ix] = pp * d[a] * d[b] + s * v[ix]; ++ix; }
            o[15] = 0.0f;
            size_t prow = (size_t)mt * 16 + h * 4 + pq;   // chunk-local point
            if (EPI == 1) {
                size_t rb = prow * 16 * 1024;
#pragma unroll
                for (int c = 0; c < 16; ++c) {
                    ushort_t hb, lb;
                    split_bf(o[c], hb, lb);
                    Anext[rb + (size_t)c * 1024 + n0 + n] = hb;
                    Anext[rb + (size_t)c * 1024 + 512 + n0 + n] = lb;
                }
            } else {
                float4* op = reinterpret_cast<float4*>(Sout + ((size_t)prow * 512 + n0 + n) * 16);
#pragma unroll
                for (int qq = 0; qq < 4; ++qq)
                    op[qq] = make_float4(o[4*qq], o[4*qq+1], o[4*qq+2], o[4*qq+3]);
            }
        }
    }
}

// ---------------- final layer + trace (validated) ----------------
__global__ __launch_bounds__(256) void trace_kernel(
    const float* __restrict__ Sin, const float* __restrict__ W3,
    const float* __restrict__ b3, float* __restrict__ out, int npts)
{
    int wave = threadIdx.x >> 6;
    int lane = threadIdx.x & 63;
    int p = blockIdx.x * 4 + wave;
    if (p >= npts) return;
    const float* sp = Sin + (size_t)p * (HDIM * NCH);

    float hu[4][10];
#pragma unroll
    for (int m = 0; m < 4; ++m)
#pragma unroll
        for (int qq = 0; qq < 10; ++qq) hu[m][qq] = 0.0f;
    float u4 = 0.0f;

    for (int kk = 0; kk < 8; ++kk) {
        int k = kk * 64 + lane;
        const float* sk = sp + k * NCH;
        float4 s0 = *reinterpret_cast<const float4*>(&sk[0]);
        float4 s1 = *reinterpret_cast<const float4*>(&sk[4]);
        float4 s2 = *reinterpret_cast<const float4*>(&sk[8]);
        float4 s3 = *reinterpret_cast<const float4*>(&sk[12]);
        float hv[10] = {s1.y,s1.z,s1.w, s2.x,s2.y,s2.z,s2.w, s3.x,s3.y,s3.z};
        float w3m[5];
#pragma unroll
        for (int m = 0; m < 5; ++m) w3m[m] = W3[m * HDIM + k];
        u4 = fmaf(w3m[4], s0.x, u4);
#pragma unroll
        for (int m = 0; m < 4; ++m)
#pragma unroll
            for (int qq = 0; qq < 10; ++qq) hu[m][qq] = fmaf(w3m[m], hv[qq], hu[m][qq]);
    }

#pragma unroll
    for (int off = 32; off > 0; off >>= 1) {
#pragma unroll
        for (int m = 0; m < 4; ++m)
#pragma unroll
            for (int qq = 0; qq < 10; ++qq) hu[m][qq] += __shfl_xor(hu[m][qq], off, 64);
        u4 += __shfl_xor(u4, off, 64);
    }

    if (lane == 0) {
        const int Pm[4][4] = {{0,1,2,3},{1,4,5,6},{2,5,7,8},{3,6,8,9}};
        const int Pd[4] = {0, 4, 7, 9};
#pragma unroll
        for (int i = 0; i < 4; ++i) {
            float t1 = hu[i][Pd[0]] + hu[i][Pd[1]] + hu[i][Pd[2]] + hu[i][Pd[3]];
            float t2 = hu[0][Pm[0][i]] + hu[1][Pm[1][i]] + hu[2][Pm[2][i]] + hu[3][Pm[3][i]];
            out[p * 5 + i] = t1 - t2;
        }
        out[p * 5 + 4] = u4 + b3[4];
    }
}

// ---------------- weight prep: W (n,k) -> BT[n][hi(512)|lo(512)] bf16 ----------------
__global__ void prep_B(const float* __restrict__ W1, const float* __restrict__ W2,
                       ushort_t* __restrict__ BT1, ushort_t* __restrict__ BT2)
{
    int tid = blockIdx.x * 256 + threadIdx.x;   // 2*512*512 total
    int l = tid >> 18;
    int i = tid & 262143;
    int n = i >> 9, k = i & 511;
    const float* W = l ? W2 : W1;
    ushort_t* BT = l ? BT2 : BT1;
    float v = W[i];
    ushort_t hb, lb;
    split_bf(v, hb, lb);
    size_t rr = (size_t)n * 1024;
    BT[rr + k] = hb;
    BT[rr + 512 + k] = lb;
}

extern "C" void kernel_launch(void* const* d_in, const int* in_sizes, int n_in,
                              void* d_out, int out_size, void* d_ws, size_t ws_size,
                              hipStream_t stream)
{
    const float* x  = (const float*)d_in[0];
    const float* W0 = (const float*)d_in[1];
    const float* b0 = (const float*)d_in[2];
    const float* W1 = (const float*)d_in[3];
    const float* b1 = (const float*)d_in[4];
    const float* W2 = (const float*)d_in[5];
    const float* b2 = (const float*)d_in[6];
    const float* W3 = (const float*)d_in[7];
    const float* b3 = (const float*)d_in[8];
    float* out = (float*)d_out;

    int B = in_sizes[0] / 4;                    // 16384 points

    ushort_t* BT1 = (ushort_t*)d_ws;            // 512*1024 bf16 each
    ushort_t* BT2 = BT1 + 512 * 1024;
    char* bufbase = (char*)(BT2 + 512 * 1024);

    size_t avail = ws_size - 2ull * 512 * 1024 * sizeof(ushort_t);
    size_t per_pt = 2ull * 32768;               // A0/A1 buffers, 32KB each per point
    int Pc = (int)(avail / per_pt) & ~15;       // multiple of 16 (BM=256 = 16 points)
    if (Pc > 16384) Pc = 16384;
    if (Pc < 16) Pc = 16;

    ushort_t* A0 = (ushort_t*)bufbase;                        // Pc*16*1024
    ushort_t* A1 = (ushort_t*)(bufbase + (size_t)Pc * 32768);
    float* S2 = (float*)A0;                                   // reuse A0 after GEMM1

    prep_B<<<2048, 256, 0, stream>>>(W1, W2, BT1, BT2);

    for (int base = 0; base < B; base += Pc) {
        int np = (B - base < Pc) ? (B - base) : Pc;
        layer0_jet<<<np, 256, 0, stream>>>(x + (size_t)base * 4, W0, b0, A0);
        int nwg = (np / 16) * 2;                // (M/256) * (N/256)
        gemm_jet10<1><<<nwg, 512, 0, stream>>>(A0, BT1, b1, A1, nullptr);
        gemm_jet10<2><<<nwg, 512, 0, stream>>>(A1, BT2, b2, nullptr, S2);
        trace_kernel<<<(np + 3) / 4, 256, 0, stream>>>(S2, W3, b3, out + (size_t)base * 5, np);
    }
}